// Round 7
// baseline (224.249 us; speedup 1.0000x reference)
//
#include <hip/hip_runtime.h>

// ---------------------------------------------------------------------------
// GCN: 3-layer, N=50000 nodes, E=800000 edges, F_IN=128, H=128, C=64.
//   norm[e] = dinv[src]*dinv[dst]  =>  fold dinv into GEMM epilogue and
//   aggregation epilogue.  Self-loop = + g[i].
//   layer: g = dinv .* (A @ W);  h = act(dinv[i]*(g[i] + sum_{j->i} g[j]) + b)
// R2: hierarchical scan. R3: G bf16. R4: bucketed counting-sort graph build.
// R5: MFMA GEMMs (16x16x32 bf16), bf16 feature path, XOR-swizzled LDS.
// R6: 8-deep gather unroll (weak: serial tail held ~30% of edges).
// R7: fully-predicated 16-deep gather (no serial tail: idx clamp + uniform
//     predicate), 512-thread agg blocks, launches 13->10 (cvtw folded into
//     hist; bscan removed -- scatter/build re-scan the 64-entry histogram).
// ---------------------------------------------------------------------------

#define NODES_PER_BUCKET 1024      // bucket = dst >> 10
#define MAX_BUCKETS 64             // n <= 64K nodes (50000 -> 49 buckets)
#define CVT_BLOCKS 160             // 40960 weight elems / 256

typedef __attribute__((ext_vector_type(8))) short short8;
typedef __attribute__((ext_vector_type(4))) float f32x4;

__device__ inline unsigned bf16_rn(float x) {          // rne, no NaN expected
    unsigned u = __float_as_uint(x);
    return (u + 0x7fffu + ((u >> 16) & 1u)) >> 16;
}
__device__ inline float bf_lo(unsigned u) { return __uint_as_float(u << 16); }
__device__ inline float bf_hi(unsigned u) { return __uint_as_float(u & 0xffff0000u); }

// ---------------------------------------------------------------------------
// prep_k: blocks [0,CVT_BLOCKS) convert W0|W1|W2 f32 -> bf16 Wt[out][128];
//         remaining blocks build the 64-bucket dst histogram.
// ---------------------------------------------------------------------------
__global__ __launch_bounds__(256) void prep_k(const int* __restrict__ dst, int e,
                                              int* __restrict__ bcnt,
                                              const float* __restrict__ W0,
                                              const float* __restrict__ W1,
                                              const float* __restrict__ W2,
                                              unsigned short* __restrict__ Wt) {
    const int t = threadIdx.x;
    if (blockIdx.x < CVT_BLOCKS) {
        int id = blockIdx.x * 256 + t;              // 0 .. 40959
        const float* W;
        int out, loc;
        if (id < 16384)      { W = W0; out = 128; loc = id; }
        else if (id < 32768) { W = W1; out = 128; loc = id - 16384; }
        else                 { W = W2; out = 64;  loc = id - 32768; }
        int o = loc >> 7, k = loc & 127;
        Wt[id] = (unsigned short)bf16_rn(W[k * out + o]);
        return;
    }
    __shared__ int h[MAX_BUCKETS];
    if (t < MAX_BUCKETS) h[t] = 0;
    __syncthreads();
    const int i0 = (blockIdx.x - CVT_BLOCKS) * 4096;
#pragma unroll
    for (int k = 0; k < 16; ++k) {
        int i = i0 + t + k * 256;
        if (i < e) atomicAdd(&h[dst[i] >> 10], 1);
    }
    __syncthreads();
    if (t < MAX_BUCKETS && h[t]) atomicAdd(&bcnt[t], h[t]);
}

// ---------------------------------------------------------------------------
// scatter_k: block-chunked pair scatter into bucket segments.  Each block
// recomputes the bucket-base scan (64 values) in its first wave; chunk
// reservation via zero-initialized scur[].
// ---------------------------------------------------------------------------
__global__ __launch_bounds__(512) void scatter_k(const int* __restrict__ src,
                                                 const int* __restrict__ dst,
                                                 int e,
                                                 const int* __restrict__ bcnt,
                                                 int* __restrict__ scur,
                                                 uint2* __restrict__ pairs) {
    __shared__ int bbase_s[MAX_BUCKETS];
    __shared__ int cnt[MAX_BUCKETS];
    __shared__ int cur[MAX_BUCKETS];
    __shared__ int gb[MAX_BUCKETS];
    const int t = threadIdx.x;
    if (t < MAX_BUCKETS) {
        int v = bcnt[t];                        // zeros beyond nbuck
        int x = v;
#pragma unroll
        for (int off = 1; off < 64; off <<= 1) {
            int y = __shfl_up(x, off);
            if ((t & 63) >= off) x += y;
        }
        bbase_s[t] = x - v;                     // exclusive scan
        cnt[t] = 0;
    }
    __syncthreads();
    const int i0 = blockIdx.x * 8192;
    int d[16];
#pragma unroll
    for (int k = 0; k < 16; ++k) {
        int i = i0 + t + k * 512;
        d[k] = (i < e) ? dst[i] : -1;
        if (d[k] >= 0) atomicAdd(&cnt[d[k] >> 10], 1);
    }
    __syncthreads();
    if (t < MAX_BUCKETS) {
        gb[t] = cnt[t] ? bbase_s[t] + atomicAdd(&scur[t], cnt[t]) : 0;
        cur[t] = 0;
    }
    __syncthreads();
#pragma unroll
    for (int k = 0; k < 16; ++k) {
        int i = i0 + t + k * 512;
        if (d[k] >= 0) {
            int b = d[k] >> 10;
            int r = atomicAdd(&cur[b], 1);
            pairs[gb[b] + r] = make_uint2((unsigned)src[i], (unsigned)d[k]);
        }
    }
}

// ---------------------------------------------------------------------------
// build_k: one 1024-thread workgroup owns one bucket; recomputes its edge
// range from bcnt, LDS histogram -> local scan -> rp/dinv/col.
// ---------------------------------------------------------------------------
__global__ __launch_bounds__(1024) void build_k(const uint2* __restrict__ pairs,
                                                const int* __restrict__ bcnt,
                                                int n, int e,
                                                int* __restrict__ rp,
                                                float* __restrict__ dinv,
                                                int* __restrict__ col) {
    __shared__ int hist[1024];
    __shared__ int tsum[1024];
    __shared__ int sE[2];
    const int t = threadIdx.x;
    const int node0 = blockIdx.x << 10;
    if (t < MAX_BUCKETS) {
        int v = bcnt[t];
        int x = v;
#pragma unroll
        for (int off = 1; off < 64; off <<= 1) {
            int y = __shfl_up(x, off);
            if ((t & 63) >= off) x += y;
        }
        if (t == blockIdx.x) { sE[0] = x - v; sE[1] = x; }
    }
    hist[t] = 0;
    __syncthreads();
    const int ebase = sE[0];
    const int eend = sE[1];
    for (int i = ebase + t; i < eend; i += 1024) {
        uint2 p = pairs[i];
        atomicAdd(&hist[(int)p.y - node0], 1);
    }
    __syncthreads();
    const int deg = hist[t];
    tsum[t] = deg;
    __syncthreads();
    for (int off = 1; off < 1024; off <<= 1) {
        int x = (t >= off) ? tsum[t - off] : 0;
        __syncthreads();
        tsum[t] += x;
        __syncthreads();
    }
    const int excl = tsum[t] - deg;
    if (node0 + t < n) {
        rp[node0 + t] = ebase + excl;
        dinv[node0 + t] = rsqrtf((float)(deg + 1));
    }
    hist[t] = excl;                       // local fill cursor
    __syncthreads();
    for (int i = ebase + t; i < eend; i += 1024) {
        uint2 p = pairs[i];
        int r = atomicAdd(&hist[(int)p.y - node0], 1);
        col[ebase + r] = (int)p.x;
    }
    if (blockIdx.x == 0 && t == 0) rp[n] = e;
}

// ---------------------------------------------------------------------------
// MFMA GEMM: G[r][c] = bf16( dinv[r] * sum_k A[r][k]*Wt[c][k] ), K=128.
// Block: 128 rows x OUT cols, 4 waves, wave = 32 rows x OUT cols.
// F32IN: stage converts f32 input rows to bf16 on the fly (layer 0).
// LDS XOR-swizzle: byte ^= ((row&7)<<4) on ds_write AND ds_read (T2).
// ---------------------------------------------------------------------------
template <int OUT, bool F32IN>
__global__ __launch_bounds__(256) void mfma_gemm_k(
    const void* __restrict__ Av,             // [n][128] bf16 or f32
    const unsigned short* __restrict__ Wt,   // [OUT][128] bf16
    const float* __restrict__ dinv,
    unsigned short* __restrict__ G,          // [n][OUT] bf16
    int n) {
    constexpr int NF = OUT / 16;             // col fragments per wave
    __shared__ unsigned short lds[(128 + OUT) * 128];
    unsigned short* As = lds;                // 128 rows x 256B (swizzled)
    unsigned short* Ws = lds + 128 * 128;    // OUT rows x 256B (swizzled)

    const int tid = threadIdx.x;
    const int row0 = blockIdx.x * 128;

    // stage A tile: 128 rows x 16 chunks of 16B (8 bf16)
#pragma unroll
    for (int p = 0; p < 8; ++p) {
        int id = p * 256 + tid;
        int r = id >> 4, c = id & 15;
        uint4 v = make_uint4(0, 0, 0, 0);
        if (row0 + r < n) {
            if (F32IN) {
                const float* Af = (const float*)Av;
                const float4* fp =
                    (const float4*)&Af[(size_t)(row0 + r) * 128 + c * 8];
                float4 v0 = fp[0], v1 = fp[1];
                v.x = bf16_rn(v0.x) | (bf16_rn(v0.y) << 16);
                v.y = bf16_rn(v0.z) | (bf16_rn(v0.w) << 16);
                v.z = bf16_rn(v1.x) | (bf16_rn(v1.y) << 16);
                v.w = bf16_rn(v1.z) | (bf16_rn(v1.w) << 16);
            } else {
                const unsigned short* Ab = (const unsigned short*)Av;
                v = *(const uint4*)&Ab[(size_t)(row0 + r) * 128 + c * 8];
            }
        }
        int bo = r * 256 + ((c * 16) ^ ((r & 7) << 4));
        *(uint4*)((char*)As + bo) = v;
    }
    // stage Wt tile: OUT rows x 16 chunks
#pragma unroll
    for (int p = 0; p < OUT / 16; ++p) {
        int id = p * 256 + tid;
        int r = id >> 4, c = id & 15;
        uint4 v = *(const uint4*)&Wt[(size_t)r * 128 + c * 8];
        int bo = r * 256 + ((c * 16) ^ ((r & 7) << 4));
        *(uint4*)((char*)Ws + bo) = v;
    }
    __syncthreads();

    const int wid = tid >> 6, lane = tid & 63;
    const int lq = lane >> 4, lr = lane & 15;
    const int woff = wid * 32;

    f32x4 acc[2][NF] = {};
#pragma unroll
    for (int ks = 0; ks < 4; ++ks) {
        short8 a[2];
#pragma unroll
        for (int m = 0; m < 2; ++m) {
            int r = woff + m * 16 + lr;
            int bo = r * 256 + ((lq * 16 + ks * 64) ^ ((r & 7) << 4));
            a[m] = *(const short8*)((const char*)As + bo);
        }
#pragma unroll
        for (int nf = 0; nf < NF; ++nf) {
            int c = nf * 16 + lr;
            int bo = c * 256 + ((lq * 16 + ks * 64) ^ ((c & 7) << 4));
            short8 b = *(const short8*)((const char*)Ws + bo);
            acc[0][nf] = __builtin_amdgcn_mfma_f32_16x16x32_bf16(a[0], b, acc[0][nf], 0, 0, 0);
            acc[1][nf] = __builtin_amdgcn_mfma_f32_16x16x32_bf16(a[1], b, acc[1][nf], 0, 0, 0);
        }
    }

    // epilogue: scale by dinv, pack bf16
#pragma unroll
    for (int m = 0; m < 2; ++m) {
#pragma unroll
        for (int j = 0; j < 4; ++j) {
            int r = row0 + woff + m * 16 + lq * 4 + j;
            if (r < n) {
                float d = dinv[r];
#pragma unroll
                for (int nf = 0; nf < NF; ++nf)
                    G[(size_t)r * OUT + nf * 16 + lr] =
                        (unsigned short)bf16_rn(d * acc[m][nf][j]);
            }
        }
    }
}

// ---------------------------------------------------------------------------
// Aggregation, hidden layers: one wave per node, lane = 2 cols (packed bf16).
// Fully-predicated 16-deep gather: every edge sits in a 16-wide batch
// (idx clamped, accumulate predicated on wave-uniform p+k<e).
// ---------------------------------------------------------------------------
__global__ __launch_bounds__(512) void agg_swish_k(const unsigned* __restrict__ G,
                                                   const int* __restrict__ rp,
                                                   const int* __restrict__ col,
                                                   const float* __restrict__ dinv,
                                                   const float* __restrict__ bias,
                                                   unsigned* __restrict__ Hb, int n) {
    const int wave = (blockIdx.x * blockDim.x + threadIdx.x) >> 6;
    const int lane = threadIdx.x & 63;
    if (wave >= n) return;
    const int i = wave;

    unsigned u = G[(size_t)i * 64 + lane];        // self-loop (row = 64 uints)
    float ax = bf_lo(u), ay = bf_hi(u);
    const int s = rp[i], e = rp[i + 1];
    for (int p = s; p < e; p += 16) {
        int j[16];
#pragma unroll
        for (int k = 0; k < 16; ++k) j[k] = col[min(p + k, e - 1)];
        unsigned v[16];
#pragma unroll
        for (int k = 0; k < 16; ++k) v[k] = G[(size_t)j[k] * 64 + lane];
#pragma unroll
        for (int k = 0; k < 16; ++k) {
            if (p + k < e) {                      // wave-uniform predicate
                ax += bf_lo(v[k]);
                ay += bf_hi(v[k]);
            }
        }
    }
    const float d = dinv[i];
    float rx = d * ax + bias[lane * 2 + 0];
    float ry = d * ay + bias[lane * 2 + 1];
    rx = rx / (1.f + expf(-rx));                  // swish
    ry = ry / (1.f + expf(-ry));
    Hb[(size_t)i * 64 + lane] = bf16_rn(rx) | (bf16_rn(ry) << 16);
}

// ---------------------------------------------------------------------------
// Final aggregation (OUT=64, bf16 rows of 128B) + log_softmax.  16-deep.
// ---------------------------------------------------------------------------
__global__ __launch_bounds__(512) void agg_lsm_k(const unsigned short* __restrict__ G,
                                                 const int* __restrict__ rp,
                                                 const int* __restrict__ col,
                                                 const float* __restrict__ dinv,
                                                 const float* __restrict__ bias,
                                                 float* __restrict__ out, int n) {
    const int wave = (blockIdx.x * blockDim.x + threadIdx.x) >> 6;
    const int lane = threadIdx.x & 63;
    if (wave >= n) return;
    const int i = wave;

    float acc = __uint_as_float((unsigned)G[(size_t)i * 64 + lane] << 16);
    const int s = rp[i], e = rp[i + 1];
    for (int p = s; p < e; p += 16) {
        int j[16];
#pragma unroll
        for (int k = 0; k < 16; ++k) j[k] = col[min(p + k, e - 1)];
        unsigned short v[16];
#pragma unroll
        for (int k = 0; k < 16; ++k) v[k] = G[(size_t)j[k] * 64 + lane];
#pragma unroll
        for (int k = 0; k < 16; ++k)
            if (p + k < e) acc += __uint_as_float((unsigned)v[k] << 16);
    }

    float logit = dinv[i] * acc + bias[lane];
    float m = logit;
#pragma unroll
    for (int off = 32; off > 0; off >>= 1) m = fmaxf(m, __shfl_xor(m, off));
    float ex = expf(logit - m);
    float ssum = ex;
#pragma unroll
    for (int off = 32; off > 0; off >>= 1) ssum += __shfl_xor(ssum, off);
    out[(size_t)i * 64 + lane] = logit - m - logf(ssum);
}

extern "C" void kernel_launch(void* const* d_in, const int* in_sizes, int n_in,
                              void* d_out, int out_size, void* d_ws, size_t ws_size,
                              hipStream_t stream) {
    const float* x = (const float*)d_in[0];
    const int* ei = (const int*)d_in[1];
    const float* W0 = (const float*)d_in[2];
    const float* b0 = (const float*)d_in[3];
    const float* W1 = (const float*)d_in[4];
    const float* b1 = (const float*)d_in[5];
    const float* W2 = (const float*)d_in[6];
    const float* b2 = (const float*)d_in[7];
    float* out = (float*)d_out;

    const int n = in_sizes[0] / 128;
    const int e = in_sizes[1] / 2;
    const int* src = ei;
    const int* dst = ei + e;

    char* ws = (char*)d_ws;
    size_t off = 0;
    auto alloc = [&](size_t bytes) -> void* {
        void* p = ws + off;
        off += (bytes + 255) & ~(size_t)255;
        return p;
    };
    int* bcnt = (int*)alloc(MAX_BUCKETS * 4 * 2);  // bcnt[64] | scur[64]
    int* scur = bcnt + MAX_BUCKETS;
    int* rp = (int*)alloc((size_t)(n + 1) * 4);    // CSR row_ptr
    float* dinv = (float*)alloc((size_t)n * 4);
    int* col = (int*)alloc((size_t)e * 4);         // CSR col (src per dst)
    uint2* pairs = (uint2*)alloc((size_t)e * 8);   // bucketed (src,dst)
    unsigned short* wt = (unsigned short*)alloc(40960 * 2);  // w0t|w1t|w2t
    unsigned short* g = (unsigned short*)alloc((size_t)n * 256);   // bf16 pre-agg
    unsigned short* hb = (unsigned short*)alloc((size_t)n * 256);  // bf16 post-act

    unsigned short* w0t = wt;
    unsigned short* w1t = wt + 16384;
    unsigned short* w2t = wt + 32768;

    const int nbuck = (n + NODES_PER_BUCKET - 1) / NODES_PER_BUCKET;  // 49

    hipMemsetAsync(bcnt, 0, MAX_BUCKETS * 4 * 2, stream);
    prep_k<<<CVT_BLOCKS + (e + 4095) / 4096, 256, 0, stream>>>(dst, e, bcnt,
                                                               W0, W1, W2, wt);
    scatter_k<<<(e + 8191) / 8192, 512, 0, stream>>>(src, dst, e, bcnt, scur, pairs);
    build_k<<<nbuck, 1024, 0, stream>>>(pairs, bcnt, n, e, rp, dinv, col);

    const int gb = (n + 127) / 128;
    const int ab = (n + 7) / 8;                    // 8 waves (nodes) per block

    mfma_gemm_k<128, true><<<gb, 256, 0, stream>>>(x, w0t, dinv, g, n);
    agg_swish_k<<<ab, 512, 0, stream>>>((const unsigned*)g, rp, col, dinv, b0,
                                        (unsigned*)hb, n);
    mfma_gemm_k<128, false><<<gb, 256, 0, stream>>>(hb, w1t, dinv, g, n);
    agg_swish_k<<<ab, 512, 0, stream>>>((const unsigned*)g, rp, col, dinv, b1,
                                        (unsigned*)hb, n);
    mfma_gemm_k<64, false><<<gb, 256, 0, stream>>>(hb, w2t, dinv, g, n);
    agg_lsm_k<<<ab, 512, 0, stream>>>(g, rp, col, dinv, b2, out, n);
}